// Round 1
// 451.159 us; speedup vs baseline: 1.0229x; 1.0229x over previous
//
#include <hip/hip_runtime.h>
#include <hip/hip_bf16.h>

#define NN 8192
#define DD 128

typedef __attribute__((ext_vector_type(8))) short short8;
typedef __attribute__((ext_vector_type(4))) float f32x4;
typedef unsigned int u32;

__device__ __forceinline__ ushort f2bf(float f) {
    __hip_bfloat16 h = __float2bfloat16(f);
    return *(ushort*)&h;
}

// async 16B/lane global->LDS; LDS dest must be wave-uniform base + lane*16.
__device__ __forceinline__ void async_ld16(const void* g, void* l) {
    __builtin_amdgcn_global_load_lds(
        (const __attribute__((address_space(1))) u32*)g,
        (__attribute__((address_space(3))) u32*)l, 16, 0, 0);
}

// ---------------- K1: Wh = X @ Ws (fp32) ----------------
// 256 blocks x 256 thr; 32 rows/block; 4x4 register tile per thread.
__global__ __launch_bounds__(256) void k1_gemm(const float* __restrict__ X,
                                               const float* __restrict__ Ws,
                                               float* __restrict__ Wh) {
    __shared__ float lWs[128 * 132];   // [k][c] pad 132
    __shared__ float lX[32 * 132];     // [r][c] pad 132
    int t = threadIdx.x, bx = blockIdx.x;
    const float4* Ws4 = (const float4*)Ws;
    const float4* X4 = (const float4*)X;
    for (int j = 0; j < 16; ++j) {
        int u = j * 256 + t;           // 0..4095 float4s of Ws
        int k = u >> 5, c4 = u & 31;
        *(float4*)&lWs[k * 132 + c4 * 4] = Ws4[u];
    }
    for (int j = 0; j < 4; ++j) {
        int u = j * 256 + t;           // 0..1023 float4s of X tile
        int r = u >> 5, c4 = u & 31;
        *(float4*)&lX[r * 132 + c4 * 4] = X4[bx * 1024 + u];
    }
    __syncthreads();
    int r0 = (t >> 5) * 4, c0 = (t & 31) * 4;
    float acc[4][4];
#pragma unroll
    for (int i = 0; i < 4; ++i)
#pragma unroll
        for (int j = 0; j < 4; ++j) acc[i][j] = 0.f;
#pragma unroll 4
    for (int k = 0; k < 128; ++k) {
        float4 wv = *(const float4*)&lWs[k * 132 + c0];
        float x0 = lX[(r0 + 0) * 132 + k];
        float x1 = lX[(r0 + 1) * 132 + k];
        float x2 = lX[(r0 + 2) * 132 + k];
        float x3 = lX[(r0 + 3) * 132 + k];
#pragma unroll
        for (int j = 0; j < 4; ++j) {
            acc[0][j] += x0 * ((const float*)&wv)[j];
            acc[1][j] += x1 * ((const float*)&wv)[j];
            acc[2][j] += x2 * ((const float*)&wv)[j];
            acc[3][j] += x3 * ((const float*)&wv)[j];
        }
    }
#pragma unroll
    for (int i = 0; i < 4; ++i)
        *(float4*)&Wh[(size_t)(bx * 32 + r0 + i) * 128 + c0] =
            (float4){acc[i][0], acc[i][1], acc[i][2], acc[i][3]};
}

// ---------------- K2: per-row scalars + coalesced bf16 transpose ----------------
// 128 blocks x 256 thr; 64 rows/block. E2 is interleaved float2 {e^s2, e^0.2*s2}.
__global__ __launch_bounds__(256) void k2_prep(const float* __restrict__ Wh,
                                               const float* __restrict__ a,
                                               ushort* __restrict__ WhT,
                                               float* __restrict__ C1,
                                               float* __restrict__ C1s,
                                               float2* __restrict__ E2) {
    __shared__ float lT[128 * 65];     // [d][r] pad 65
    __shared__ float la[256];
    int t = threadIdx.x;
    int i0 = blockIdx.x * 64;
    la[t] = a[t];
    for (int j = 0; j < 32; ++j) {
        int u = j * 256 + t;           // 0..8191
        int r = u >> 7, c = u & 127;
        lT[c * 65 + r] = Wh[(size_t)(i0 + r) * 128 + c];
    }
    __syncthreads();
    // s1/s2: 4 threads per row
    int r = t >> 2, q = t & 3;
    float s1 = 0.f, s2 = 0.f;
    for (int j = 0; j < 32; ++j) {
        int d = q * 32 + j;
        float v = lT[d * 65 + r];
        s1 += v * la[d];
        s2 += v * la[128 + d];
    }
    s1 += __shfl_xor(s1, 1); s1 += __shfl_xor(s1, 2);
    s2 += __shfl_xor(s2, 1); s2 += __shfl_xor(s2, 2);
    if (q == 0) {
        int i = i0 + r;
        C1[i]  = __expf(s1);
        C1s[i] = __expf(0.2f * s1);
        E2[i]  = make_float2(__expf(s2), __expf(0.2f * s2));
    }
    // WhT: thread t -> d=t>>1, half=t&1; 32 contiguous ushorts (64 B)
    int d = t >> 1, hf = t & 1;
    __attribute__((aligned(16))) ushort tmp[32];
#pragma unroll
    for (int s = 0; s < 32; ++s) tmp[s] = f2bf(lT[d * 65 + hf * 32 + s]);
    uint4* dst = (uint4*)&WhT[(size_t)d * NN + i0 + hf * 32];
    const uint4* srcv = (const uint4*)tmp;
#pragma unroll
    for (int s = 0; s < 4; ++s) dst[s] = srcv[s];
}

// ---------------- K0: bit-pack A + zero the atomic accumulators ----------------
// Ap dword index = (kt*NN + row)*4 + kg; byte tp of that dword holds bits
// A[row][kt*128 + tp*32 + kg*8 + j] (j = bit 0..7). One dword = lane's mask
// for a full 128-wide k-tile in k3.
__global__ __launch_bounds__(256) void k0_pack(const int* __restrict__ A,
                                               u32* __restrict__ Ap,
                                               float* __restrict__ Hp,
                                               float* __restrict__ Lp) {
    u32 u = blockIdx.x * 256 + threadIdx.x;   // 0 .. 2M-1
    if (u < (u32)(NN * DD)) Hp[u] = 0.f;
    if (u < (u32)NN) Lp[u] = 0.f;
    u32 kt = u >> 15;                 // 32768 dwords per k-tile
    u32 row = (u >> 2) & (NN - 1);
    u32 kg = u & 3;
    const int* base = A + (size_t)row * NN + kt * 128 + kg * 8;
    u32 d = 0;
#pragma unroll
    for (int tp = 0; tp < 4; ++tp) {
        int4 lo = *(const int4*)(base + tp * 32);
        int4 hi = *(const int4*)(base + tp * 32 + 4);
        u32 b = 0;
        b |= (lo.x != 0) ? 1u : 0u;
        b |= (lo.y != 0) ? 2u : 0u;
        b |= (lo.z != 0) ? 4u : 0u;
        b |= (lo.w != 0) ? 8u : 0u;
        b |= (hi.x != 0) ? 16u : 0u;
        b |= (hi.y != 0) ? 32u : 0u;
        b |= (hi.z != 0) ? 64u : 0u;
        b |= (hi.w != 0) ? 128u : 0u;
        d |= b << (8 * tp);
    }
    Ap[u] = d;
}

// ---------------- K3: masked-softmax GEMM (restructured) ----------------
// grid (64 rowblocks, 8 ksplit) x 512 thr (8 waves). Each wave owns 16 rows
// and ALL 128 cols -> exp-weight af built exactly once per (row,k).
// A: packed bits, 1 dword/lane/tile from registers (prefetched).
// B (WhT) + E2: DMA-staged double-buffered LDS (66 KB -> 2 blocks/CU).
// Row sums via MFMA against all-ones B. Partials accumulate via atomicAdd.
__global__ __launch_bounds__(512, 4) void k3_main(
    const u32* __restrict__ Ap, const ushort* __restrict__ WhT,
    const float* __restrict__ C1, const float* __restrict__ C1s,
    const float2* __restrict__ E2,
    float* __restrict__ Hp, float* __restrict__ Lp) {

    __shared__ __align__(16) char lB[2 * 32768];  // [buf][(tp*8+c)*1024 + lane*16]
    __shared__ __align__(16) char lE[2 * 1024];   // [buf][float2 pairs for 128 k]

    int tid = threadIdx.x;
    int lane = tid & 63;
    int w = tid >> 6;           // 8 waves
    int n = lane & 15;
    int kg = lane >> 4;

    int bx = blockIdx.x;        // 64 row-blocks
    int kb = blockIdx.y;        // 8 k-splits
    int rb = bx * 128 + w * 16; // wave's 16 rows
    int row = rb + n;
    int kt0 = kb * 8;           // global k-tile base (tiles of 128)

    float c1 = C1[row], c1s = C1s[row];

    // B staging: wave stages fragments p = 4w .. 4w+3 (p = tp*8 + c)
    const char* srcB[4];
    char* dstB[4];
#pragma unroll
    for (int i = 0; i < 4; ++i) {
        int p = 4 * w + i;
        int c = p & 7, tp = p >> 3;
        srcB[i] = (const char*)(WhT + (size_t)(c * 16 + n) * NN +
                                (size_t)kt0 * 128 + tp * 32 + kg * 8);
        dstB[i] = lB + p * 1024 + lane * 16;
    }
    const char* srcE = (const char*)(E2 + (size_t)kt0 * 128) + lane * 16;

    const u32* pA = Ap + ((size_t)kt0 * NN + row) * 4 + kg;
    u32 a_cur = pA[0];
    u32 a_nxt = 0;

    // prologue: stage tile 0 -> buf0
#pragma unroll
    for (int i = 0; i < 4; ++i) async_ld16(srcB[i], dstB[i]);
    if (w == 0) async_ld16(srcE, lE + lane * 16);

    short8 ones;
#pragma unroll
    for (int j = 0; j < 8; ++j) ones[j] = (short)0x3F80;  // bf16 1.0

    f32x4 acc[8];
#pragma unroll
    for (int c = 0; c < 8; ++c) acc[c] = (f32x4){0.f, 0.f, 0.f, 0.f};
    f32x4 accl = (f32x4){0.f, 0.f, 0.f, 0.f};

    __syncthreads();

    for (int kt = 0; kt < 8; ++kt) {
        int buf = kt & 1;
        if (kt < 7) {   // stage next tile into other buffer (drained by end barrier)
            int bo = (buf ^ 1) * 32768;
#pragma unroll
            for (int i = 0; i < 4; ++i)
                async_ld16(srcB[i] + (kt + 1) * 256, dstB[i] + bo);
            if (w == 0)
                async_ld16(srcE + (kt + 1) * 1024, lE + (buf ^ 1) * 1024 + lane * 16);
            a_nxt = pA[(size_t)(kt + 1) * (NN * 4)];
        }
        const char* bB = lB + buf * 32768;
        const float* bE = (const float*)(lE + buf * 1024);
#pragma unroll
        for (int tp = 0; tp < 4; ++tp) {
            // 8 (ep,en) pairs for this lane's 8 k-slots (broadcast across n)
            const float4* ev = (const float4*)(bE + (tp * 32 + kg * 8) * 2);
            float pe[16];
            *(float4*)(pe + 0)  = ev[0];
            *(float4*)(pe + 4)  = ev[1];
            *(float4*)(pe + 8)  = ev[2];
            *(float4*)(pe + 12) = ev[3];
            u32 ab = (a_cur >> (tp * 8)) & 0xffu;
            short8 af;
#pragma unroll
            for (int u = 0; u < 8; ++u) {
                // exp(leaky(s1+s2)) = max(e^s1 e^s2, e^.2s1 e^.2s2)
                float wv = fmaxf(c1 * pe[2 * u], c1s * pe[2 * u + 1]);
                af[u] = ((ab >> u) & 1u) ? (short)f2bf(wv) : (short)0;
            }
            const short8* bb = (const short8*)(bB + tp * 8192);
#pragma unroll
            for (int c = 0; c < 8; ++c)
                acc[c] = __builtin_amdgcn_mfma_f32_16x16x32_bf16(
                    af, bb[c * 64 + lane], acc[c], 0, 0, 0);
            accl = __builtin_amdgcn_mfma_f32_16x16x32_bf16(af, ones, accl, 0, 0, 0);
        }
        a_cur = a_nxt;
        __syncthreads();
    }

    // epilogue. C/D layout: col = lane&15, row = (lane>>4)*4 + reg  [m89]
#pragma unroll
    for (int c = 0; c < 8; ++c)
#pragma unroll
        for (int r = 0; r < 4; ++r)
            atomicAdd(&Hp[(size_t)(rb + kg * 4 + r) * DD + c * 16 + n], acc[c][r]);
    if (n == 0)
#pragma unroll
        for (int r = 0; r < 4; ++r)
            atomicAdd(&Lp[rb + kg * 4 + r], accl[r]);
}

// ---------------- K4: normalize ----------------
__global__ void k4_final(const float* __restrict__ Hp, const float* __restrict__ Lp,
                         float* __restrict__ out) {
    int idx = blockIdx.x * 256 + threadIdx.x;
    out[idx] = Hp[idx] / Lp[idx >> 7];
}

extern "C" void kernel_launch(void* const* d_in, const int* in_sizes, int n_in,
                              void* d_out, int out_size, void* d_ws, size_t ws_size,
                              hipStream_t stream) {
    const int*   A  = (const int*)d_in[0];
    const float* X  = (const float*)d_in[1];
    const float* Ws = (const float*)d_in[2];
    const float* a  = (const float*)d_in[3];
    float* out = (float*)d_out;

    char* ws = (char*)d_ws;
    // Layout (total ~14.2 MB):
    //   [0, 8M)        Ap  (k0 writes; k3 reads)  -- Wh overlaid at [0,4M) for k1/k2
    //   [8M, 10M)      WhT bf16
    //   [10M, +32K)    C1
    //   [+32K, +64K)   C1s
    //   [+64K, +128K)  E2 (float2)
    //   [10M+128K, 14M+128K) Hp (atomic accumulator)
    //   [14M+128K, +32K)     Lp (atomic accumulator)
    u32*    Ap  = (u32*)(ws);
    float*  Wh  = (float*)(ws);                          // dead after k2; k0 overwrites
    ushort* WhT = (ushort*)(ws + (8u << 20));
    float*  C1  = (float*)(ws + (10u << 20));
    float*  C1s = (float*)(ws + (10u << 20) + (32u << 10));
    float2* E2  = (float2*)(ws + (10u << 20) + (64u << 10));
    float*  Hp  = (float*)(ws + (10u << 20) + (128u << 10));
    float*  Lp  = (float*)(ws + (14u << 20) + (128u << 10));

    k1_gemm<<<256, 256, 0, stream>>>(X, Ws, Wh);
    k2_prep<<<128, 256, 0, stream>>>(Wh, a, WhT, C1, C1s, E2);
    k0_pack<<<8192, 256, 0, stream>>>(A, Ap, Hp, Lp);   // also zeroes Hp/Lp
    k3_main<<<dim3(64, 8), 512, 0, stream>>>(Ap, WhT, C1, C1s, E2, Hp, Lp);
    k4_final<<<4096, 256, 0, stream>>>(Hp, Lp, out);
}

// Round 2
// 446.346 us; speedup vs baseline: 1.0339x; 1.0108x over previous
//
#include <hip/hip_runtime.h>
#include <hip/hip_bf16.h>

#define NN 8192
#define DD 128

typedef __attribute__((ext_vector_type(8))) short short8;
typedef __attribute__((ext_vector_type(4))) float f32x4;
typedef unsigned int u32;

__device__ __forceinline__ ushort f2bf(float f) {
    __hip_bfloat16 h = __float2bfloat16(f);
    return *(ushort*)&h;
}

// async 16B/lane global->LDS; LDS dest must be wave-uniform base + lane*16.
__device__ __forceinline__ void async_ld16(const void* g, void* l) {
    __builtin_amdgcn_global_load_lds(
        (const __attribute__((address_space(1))) u32*)g,
        (__attribute__((address_space(3))) u32*)l, 16, 0, 0);
}

// ---------------- K1: Wh = X @ Ws (fp32) ----------------
// 256 blocks x 256 thr; 32 rows/block; 4x4 register tile per thread.
__global__ __launch_bounds__(256) void k1_gemm(const float* __restrict__ X,
                                               const float* __restrict__ Ws,
                                               float* __restrict__ Wh) {
    __shared__ float lWs[128 * 132];   // [k][c] pad 132
    __shared__ float lX[32 * 132];     // [r][c] pad 132
    int t = threadIdx.x, bx = blockIdx.x;
    const float4* Ws4 = (const float4*)Ws;
    const float4* X4 = (const float4*)X;
    for (int j = 0; j < 16; ++j) {
        int u = j * 256 + t;           // 0..4095 float4s of Ws
        int k = u >> 5, c4 = u & 31;
        *(float4*)&lWs[k * 132 + c4 * 4] = Ws4[u];
    }
    for (int j = 0; j < 4; ++j) {
        int u = j * 256 + t;           // 0..1023 float4s of X tile
        int r = u >> 5, c4 = u & 31;
        *(float4*)&lX[r * 132 + c4 * 4] = X4[bx * 1024 + u];
    }
    __syncthreads();
    int r0 = (t >> 5) * 4, c0 = (t & 31) * 4;
    float acc[4][4];
#pragma unroll
    for (int i = 0; i < 4; ++i)
#pragma unroll
        for (int j = 0; j < 4; ++j) acc[i][j] = 0.f;
#pragma unroll 4
    for (int k = 0; k < 128; ++k) {
        float4 wv = *(const float4*)&lWs[k * 132 + c0];
        float x0 = lX[(r0 + 0) * 132 + k];
        float x1 = lX[(r0 + 1) * 132 + k];
        float x2 = lX[(r0 + 2) * 132 + k];
        float x3 = lX[(r0 + 3) * 132 + k];
#pragma unroll
        for (int j = 0; j < 4; ++j) {
            acc[0][j] += x0 * ((const float*)&wv)[j];
            acc[1][j] += x1 * ((const float*)&wv)[j];
            acc[2][j] += x2 * ((const float*)&wv)[j];
            acc[3][j] += x3 * ((const float*)&wv)[j];
        }
    }
#pragma unroll
    for (int i = 0; i < 4; ++i)
        *(float4*)&Wh[(size_t)(bx * 32 + r0 + i) * 128 + c0] =
            (float4){acc[i][0], acc[i][1], acc[i][2], acc[i][3]};
}

// ---------------- K2: per-row scalars + coalesced bf16 transpose ----------------
// 128 blocks x 256 thr; 64 rows/block. E2 is interleaved float2 {e^s2, e^0.2*s2}.
__global__ __launch_bounds__(256) void k2_prep(const float* __restrict__ Wh,
                                               const float* __restrict__ a,
                                               ushort* __restrict__ WhT,
                                               float* __restrict__ C1,
                                               float* __restrict__ C1s,
                                               float2* __restrict__ E2) {
    __shared__ float lT[128 * 65];     // [d][r] pad 65
    __shared__ float la[256];
    int t = threadIdx.x;
    int i0 = blockIdx.x * 64;
    la[t] = a[t];
    for (int j = 0; j < 32; ++j) {
        int u = j * 256 + t;           // 0..8191
        int r = u >> 7, c = u & 127;
        lT[c * 65 + r] = Wh[(size_t)(i0 + r) * 128 + c];
    }
    __syncthreads();
    // s1/s2: 4 threads per row
    int r = t >> 2, q = t & 3;
    float s1 = 0.f, s2 = 0.f;
    for (int j = 0; j < 32; ++j) {
        int d = q * 32 + j;
        float v = lT[d * 65 + r];
        s1 += v * la[d];
        s2 += v * la[128 + d];
    }
    s1 += __shfl_xor(s1, 1); s1 += __shfl_xor(s1, 2);
    s2 += __shfl_xor(s2, 1); s2 += __shfl_xor(s2, 2);
    if (q == 0) {
        int i = i0 + r;
        C1[i]  = __expf(s1);
        C1s[i] = __expf(0.2f * s1);
        E2[i]  = make_float2(__expf(s2), __expf(0.2f * s2));
    }
    // WhT: thread t -> d=t>>1, half=t&1; 32 contiguous ushorts (64 B)
    int d = t >> 1, hf = t & 1;
    __attribute__((aligned(16))) ushort tmp[32];
#pragma unroll
    for (int s = 0; s < 32; ++s) tmp[s] = f2bf(lT[d * 65 + hf * 32 + s]);
    uint4* dst = (uint4*)&WhT[(size_t)d * NN + i0 + hf * 32];
    const uint4* srcv = (const uint4*)tmp;
#pragma unroll
    for (int s = 0; s < 4; ++s) dst[s] = srcv[s];
}

// ---------------- K0: bit-pack A ----------------
// Ap dword index = (kt*NN + row)*4 + kg; byte tp of that dword holds bits
// A[row][kt*128 + tp*32 + kg*8 + j] (j = bit 0..7). One dword = lane's mask
// for a full 128-wide k-tile in k3.
__global__ __launch_bounds__(256) void k0_pack(const int* __restrict__ A,
                                               u32* __restrict__ Ap) {
    u32 u = blockIdx.x * 256 + threadIdx.x;   // 0 .. 2M-1
    u32 kt = u >> 15;                 // 32768 dwords per k-tile
    u32 row = (u >> 2) & (NN - 1);
    u32 kg = u & 3;
    const int* base = A + (size_t)row * NN + kt * 128 + kg * 8;
    u32 d = 0;
#pragma unroll
    for (int tp = 0; tp < 4; ++tp) {
        int4 lo = *(const int4*)(base + tp * 32);
        int4 hi = *(const int4*)(base + tp * 32 + 4);
        u32 b = 0;
        b |= (lo.x != 0) ? 1u : 0u;
        b |= (lo.y != 0) ? 2u : 0u;
        b |= (lo.z != 0) ? 4u : 0u;
        b |= (lo.w != 0) ? 8u : 0u;
        b |= (hi.x != 0) ? 16u : 0u;
        b |= (hi.y != 0) ? 32u : 0u;
        b |= (hi.z != 0) ? 64u : 0u;
        b |= (hi.w != 0) ? 128u : 0u;
        d |= b << (8 * tp);
    }
    Ap[u] = d;
}

// ---------------- K3: masked-softmax GEMM ----------------
// grid (64 rowblocks, 8 ksplit) x 256 thr (4 waves). Each wave owns 32 rows
// (two 16-row groups) and ALL 128 cols: every B-fragment ds_read feeds TWO
// MFMAs (halves LDS-read per FLOP; LDS pipe is the bottleneck), and the
// exp-weight af is built exactly once per (row,k) globally.
// A: packed bits, 2 dwords/lane/tile from registers (prefetched).
// B (WhT) + E2: DMA-staged double-buffered LDS (66 KB -> 2 blocks/CU).
// Row sums via MFMA against all-ones B. Split-K partials; NO atomics.
__global__ __launch_bounds__(256, 2) void k3_main(
    const u32* __restrict__ Ap, const ushort* __restrict__ WhT,
    const float* __restrict__ C1, const float* __restrict__ C1s,
    const float2* __restrict__ E2,
    float* __restrict__ Hp, float* __restrict__ Lp) {

    __shared__ __align__(16) char lB[2 * 32768];  // [buf][(tp*8+c)*1024 + lane*16]
    __shared__ __align__(16) char lE[2 * 1024];   // [buf][float2 pairs for 128 k]

    int tid = threadIdx.x;
    int lane = tid & 63;
    int w = tid >> 6;           // 4 waves
    int n = lane & 15;
    int kg = lane >> 4;

    int bx = blockIdx.x;        // 64 row-blocks (128 rows each)
    int kb = blockIdx.y;        // 8 k-splits
    int rb = bx * 128 + w * 32; // wave's 32 rows (two 16-row groups)
    int kt0 = kb * 8;           // global k-tile base (tiles of 128)

    float c1_0 = C1[rb + n],      c1s_0 = C1s[rb + n];
    float c1_1 = C1[rb + 16 + n], c1s_1 = C1s[rb + 16 + n];

    // B staging: wave w stages tp=w, all 8 col-fragments (p = w*8 + c)
    const char* srcB[8];
    char* dstB[8];
#pragma unroll
    for (int i = 0; i < 8; ++i) {
        srcB[i] = (const char*)(WhT + (size_t)(i * 16 + n) * NN +
                                (size_t)kt0 * 128 + w * 32 + kg * 8);
        dstB[i] = lB + (w * 8 + i) * 1024 + lane * 16;
    }
    const char* srcE = (const char*)(E2 + (size_t)kt0 * 128) + lane * 16;

    const u32* pA0 = Ap + ((size_t)kt0 * NN + rb + n) * 4 + kg;
    const u32* pA1 = pA0 + 64;   // +16 rows
    u32 a_cur0 = pA0[0], a_cur1 = pA1[0];
    u32 a_nxt0 = 0, a_nxt1 = 0;

    // prologue: stage tile 0 -> buf0
#pragma unroll
    for (int i = 0; i < 8; ++i) async_ld16(srcB[i], dstB[i]);
    if (w == 0) async_ld16(srcE, lE + lane * 16);

    short8 ones;
#pragma unroll
    for (int j = 0; j < 8; ++j) ones[j] = (short)0x3F80;  // bf16 1.0

    f32x4 acc0[8], acc1[8];
#pragma unroll
    for (int c = 0; c < 8; ++c) {
        acc0[c] = (f32x4){0.f, 0.f, 0.f, 0.f};
        acc1[c] = (f32x4){0.f, 0.f, 0.f, 0.f};
    }
    f32x4 accl0 = (f32x4){0.f, 0.f, 0.f, 0.f};
    f32x4 accl1 = (f32x4){0.f, 0.f, 0.f, 0.f};

    __syncthreads();

    for (int kt = 0; kt < 8; ++kt) {
        int buf = kt & 1;
        if (kt < 7) {   // stage next tile into other buffer (drained by end barrier)
            int bo = (buf ^ 1) * 32768;
#pragma unroll
            for (int i = 0; i < 8; ++i)
                async_ld16(srcB[i] + (kt + 1) * 256, dstB[i] + bo);
            if (w == 0)
                async_ld16(srcE + (kt + 1) * 1024, lE + (buf ^ 1) * 1024 + lane * 16);
            a_nxt0 = pA0[(size_t)(kt + 1) * (NN * 4)];
            a_nxt1 = pA1[(size_t)(kt + 1) * (NN * 4)];
        }
        const char* bB = lB + buf * 32768;
        const float* bE = (const float*)(lE + buf * 1024);
#pragma unroll
        for (int tp = 0; tp < 4; ++tp) {
            // 8 (ep,en) pairs for this lane's 8 k-slots (broadcast across n)
            const float4* ev = (const float4*)(bE + (tp * 32 + kg * 8) * 2);
            float pe[16];
            *(float4*)(pe + 0)  = ev[0];
            *(float4*)(pe + 4)  = ev[1];
            *(float4*)(pe + 8)  = ev[2];
            *(float4*)(pe + 12) = ev[3];
            u32 ab0 = (a_cur0 >> (tp * 8)) & 0xffu;
            u32 ab1 = (a_cur1 >> (tp * 8)) & 0xffu;
            short8 af0, af1;
#pragma unroll
            for (int u = 0; u < 8; ++u) {
                // exp(leaky(s1+s2)) = max(e^s1 e^s2, e^.2s1 e^.2s2)
                float w0 = fmaxf(c1_0 * pe[2 * u], c1s_0 * pe[2 * u + 1]);
                float w1 = fmaxf(c1_1 * pe[2 * u], c1s_1 * pe[2 * u + 1]);
                af0[u] = ((ab0 >> u) & 1u) ? (short)f2bf(w0) : (short)0;
                af1[u] = ((ab1 >> u) & 1u) ? (short)f2bf(w1) : (short)0;
            }
            const short8* bb = (const short8*)(bB + tp * 8192);
#pragma unroll
            for (int c = 0; c < 8; ++c) {
                short8 bf = bb[c * 64 + lane];   // read ONCE, feed two MFMAs
                acc0[c] = __builtin_amdgcn_mfma_f32_16x16x32_bf16(af0, bf, acc0[c], 0, 0, 0);
                acc1[c] = __builtin_amdgcn_mfma_f32_16x16x32_bf16(af1, bf, acc1[c], 0, 0, 0);
            }
            accl0 = __builtin_amdgcn_mfma_f32_16x16x32_bf16(af0, ones, accl0, 0, 0, 0);
            accl1 = __builtin_amdgcn_mfma_f32_16x16x32_bf16(af1, ones, accl1, 0, 0, 0);
        }
        a_cur0 = a_nxt0;
        a_cur1 = a_nxt1;
        __syncthreads();
    }

    // epilogue. C/D layout: col = lane&15, row = (lane>>4)*4 + reg  [m89]
    float* Hpb = Hp + (size_t)kb * (NN * DD);
#pragma unroll
    for (int c = 0; c < 8; ++c)
#pragma unroll
        for (int r = 0; r < 4; ++r) {
            Hpb[(size_t)(rb + kg * 4 + r) * DD + c * 16 + n]      = acc0[c][r];
            Hpb[(size_t)(rb + 16 + kg * 4 + r) * DD + c * 16 + n] = acc1[c][r];
        }
    if (n == 0) {
        float* Lpb = Lp + (size_t)kb * NN;
#pragma unroll
        for (int r = 0; r < 4; ++r) {
            Lpb[rb + kg * 4 + r]      = accl0[r];
            Lpb[rb + 16 + kg * 4 + r] = accl1[r];
        }
    }
}

// ---------------- K4: combine split-K partials, normalize ----------------
__global__ void k4_final(const float* __restrict__ Hp, const float* __restrict__ Lp,
                         float* __restrict__ out) {
    int idx = blockIdx.x * 256 + threadIdx.x;
    int i = idx >> 7;
    float sv = 0.f, l = 0.f;
#pragma unroll
    for (int kb = 0; kb < 8; ++kb) {
        sv += Hp[(size_t)kb * (NN * DD) + idx];
        l  += Lp[(size_t)kb * NN + i];
    }
    out[idx] = sv / l;
}

extern "C" void kernel_launch(void* const* d_in, const int* in_sizes, int n_in,
                              void* d_out, int out_size, void* d_ws, size_t ws_size,
                              hipStream_t stream) {
    const int*   A  = (const int*)d_in[0];
    const float* X  = (const float*)d_in[1];
    const float* Ws = (const float*)d_in[2];
    const float* a  = (const float*)d_in[3];
    float* out = (float*)d_out;

    char* ws = (char*)d_ws;
    // Layout (~42.5 MB):
    //   [0, 8M)         Ap  (k0 writes; k3 reads) -- Wh overlaid at [0,4M) for k1/k2
    //   [8M, 10M)       WhT bf16
    //   [10M, +32K)     C1
    //   [+32K, +64K)    C1s
    //   [+64K, +128K)   E2 (float2)
    //   [10M+128K, +32M)  Hp (8 split-K partials, 4MB each)
    //   [42M+128K, +256K) Lp (8 partials, 32KB each)
    u32*    Ap  = (u32*)(ws);
    float*  Wh  = (float*)(ws);                          // dead after k2; k0 overwrites
    ushort* WhT = (ushort*)(ws + (8u << 20));
    float*  C1  = (float*)(ws + (10u << 20));
    float*  C1s = (float*)(ws + (10u << 20) + (32u << 10));
    float2* E2  = (float2*)(ws + (10u << 20) + (64u << 10));
    float*  Hp  = (float*)(ws + (10u << 20) + (128u << 10));
    float*  Lp  = (float*)(ws + (42u << 20) + (128u << 10));

    k1_gemm<<<256, 256, 0, stream>>>(X, Ws, Wh);
    k2_prep<<<128, 256, 0, stream>>>(Wh, a, WhT, C1, C1s, E2);
    k0_pack<<<8192, 256, 0, stream>>>(A, Ap);
    k3_main<<<dim3(64, 8), 256, 0, stream>>>(Ap, WhT, C1, C1s, E2, Hp, Lp);
    k4_final<<<4096, 256, 0, stream>>>(Hp, Lp, out);
}

// Round 4
// 424.028 us; speedup vs baseline: 1.0884x; 1.0526x over previous
//
#include <hip/hip_runtime.h>
#include <hip/hip_bf16.h>

#define NN 8192
#define DD 128

typedef __attribute__((ext_vector_type(8))) short short8;
typedef __attribute__((ext_vector_type(4))) float f32x4;
typedef __attribute__((ext_vector_type(4))) int i32x4;
typedef unsigned int u32;

__device__ __forceinline__ ushort f2bf(float f) {
    __hip_bfloat16 h = __float2bfloat16(f);
    return *(ushort*)&h;
}

// async 16B/lane global->LDS; LDS dest must be wave-uniform base + lane*16.
__device__ __forceinline__ void async_ld16(const void* g, void* l) {
    __builtin_amdgcn_global_load_lds(
        (const __attribute__((address_space(1))) u32*)g,
        (__attribute__((address_space(3))) u32*)l, 16, 0, 0);
}

// ---------------- K12: Wh = X @ Ws fused with per-row scalars + bf16 transpose ----
// 256 blocks x 256 thr; 32 rows/block; 4x4 register tile per thread.
// At end of k-loop each thread's acc holds Wh[r0..r0+3][c0..c0+3]; reduce
// across the 32 threads of a row-group for s1/s2 (shfl), and emit WhT bf16
// through an 8KB LDS transpose tile. Wh fp32 never touches HBM.
__global__ __launch_bounds__(256) void k12_gemm(const float* __restrict__ X,
                                                const float* __restrict__ Ws,
                                                const float* __restrict__ a,
                                                ushort* __restrict__ WhT,
                                                float* __restrict__ C1,
                                                float* __restrict__ C1s,
                                                float2* __restrict__ E2) {
    __shared__ float lWs[128 * 132];   // [k][c] pad 132
    __shared__ float lX[32 * 132];     // [r][c] pad 132
    __shared__ ushort lT2[128 * 32];   // [c][r] bf16 transpose staging
    __shared__ float la[256];
    int t = threadIdx.x, bx = blockIdx.x;
    la[t] = a[t];
    const float4* Ws4 = (const float4*)Ws;
    const float4* X4 = (const float4*)X;
    for (int j = 0; j < 16; ++j) {
        int u = j * 256 + t;           // 0..4095 float4s of Ws
        int k = u >> 5, c4 = u & 31;
        *(float4*)&lWs[k * 132 + c4 * 4] = Ws4[u];
    }
    for (int j = 0; j < 4; ++j) {
        int u = j * 256 + t;           // 0..1023 float4s of X tile
        int r = u >> 5, c4 = u & 31;
        *(float4*)&lX[r * 132 + c4 * 4] = X4[bx * 1024 + u];
    }
    __syncthreads();
    int r0 = (t >> 5) * 4, c0 = (t & 31) * 4;
    float acc[4][4];
#pragma unroll
    for (int i = 0; i < 4; ++i)
#pragma unroll
        for (int j = 0; j < 4; ++j) acc[i][j] = 0.f;
#pragma unroll 4
    for (int k = 0; k < 128; ++k) {
        float4 wv = *(const float4*)&lWs[k * 132 + c0];
        float x0 = lX[(r0 + 0) * 132 + k];
        float x1 = lX[(r0 + 1) * 132 + k];
        float x2 = lX[(r0 + 2) * 132 + k];
        float x3 = lX[(r0 + 3) * 132 + k];
#pragma unroll
        for (int j = 0; j < 4; ++j) {
            acc[0][j] += x0 * ((const float*)&wv)[j];
            acc[1][j] += x1 * ((const float*)&wv)[j];
            acc[2][j] += x2 * ((const float*)&wv)[j];
            acc[3][j] += x3 * ((const float*)&wv)[j];
        }
    }
    // bf16 transpose staging
#pragma unroll
    for (int i = 0; i < 4; ++i)
#pragma unroll
        for (int j = 0; j < 4; ++j)
            lT2[(c0 + j) * 32 + r0 + i] = f2bf(acc[i][j]);
    // per-row scalars: s1 = Wh[r].a1, s2 = Wh[r].a2
    float p1[4], p2[4];
#pragma unroll
    for (int i = 0; i < 4; ++i) {
        p1[i] = 0.f; p2[i] = 0.f;
#pragma unroll
        for (int j = 0; j < 4; ++j) {
            p1[i] += acc[i][j] * la[c0 + j];
            p2[i] += acc[i][j] * la[128 + c0 + j];
        }
    }
#pragma unroll
    for (int m = 1; m < 32; m <<= 1) {
#pragma unroll
        for (int i = 0; i < 4; ++i) {
            p1[i] += __shfl_xor(p1[i], m);
            p2[i] += __shfl_xor(p2[i], m);
        }
    }
    if ((t & 31) == 0) {
#pragma unroll
        for (int i = 0; i < 4; ++i) {
            int row = bx * 32 + r0 + i;
            C1[row]  = __expf(p1[i]);
            C1s[row] = __expf(0.2f * p1[i]);
            E2[row]  = make_float2(__expf(p2[i]), __expf(0.2f * p2[i]));
        }
    }
    __syncthreads();
    // WhT[d][srcrow]: thread t -> d=t>>1, half=t&1; 32B contiguous
    {
        int d = t >> 1, hf = t & 1;
        uint4* dst = (uint4*)&WhT[(size_t)d * NN + bx * 32 + hf * 16];
        const uint4* src = (const uint4*)&lT2[d * 32 + hf * 16];
        dst[0] = src[0];
        dst[1] = src[1];
    }
}

// ---------------- K3: masked-softmax GEMM, A streamed + packed in-kernel ----------
// grid (64 rowblocks, 8 ksplit) x 256 thr (4 waves). Each wave owns 32 rows
// (two 16-row groups) and ALL 128 cols: every B-fragment ds_read feeds TWO
// MFMAs, exp-weight built once per (row,k) globally.
// A: int32 0/1, loaded direct from HBM one tile ahead into 16 i32x4 regs,
// packed to 2 mask dwords after the MFMA section (the vmcnt wait lands where
// the HBM-BW floor forces a wait anyway). Nontemporal: one-shot stream, keep
// WhT resident in L2.
// B (WhT) + E2: DMA-staged double-buffered LDS (66 KB -> 2 blocks/CU).
// Row sums via MFMA against all-ones B. Split-K partials; NO atomics.
#define PACK4(b, v, sh)                                     \
    b |= (u32)((v).x & 1) << (sh);                          \
    b |= (u32)((v).y & 1) << ((sh) + 1);                    \
    b |= (u32)((v).z & 1) << ((sh) + 2);                    \
    b |= (u32)((v).w & 1) << ((sh) + 3);

__global__ __launch_bounds__(256, 2) void k3_main(
    const int* __restrict__ A, const ushort* __restrict__ WhT,
    const float* __restrict__ C1, const float* __restrict__ C1s,
    const float2* __restrict__ E2,
    float* __restrict__ Hp, float* __restrict__ Lp) {

    __shared__ __align__(16) char lB[2 * 32768];  // [buf][(tp*8+c)*1024 + lane*16]
    __shared__ __align__(16) char lE[2 * 1024];   // [buf][float2 pairs for 128 k]

    int tid = threadIdx.x;
    int lane = tid & 63;
    int w = tid >> 6;           // 4 waves
    int n = lane & 15;
    int kg = lane >> 4;

    int bx = blockIdx.x;        // 64 row-blocks (128 rows each)
    int kb = blockIdx.y;        // 8 k-splits
    int rb = bx * 128 + w * 32; // wave's 32 rows (two 16-row groups)
    int kt0 = kb * 8;           // global k-tile base (tiles of 128)

    float c1_0 = C1[rb + n],      c1s_0 = C1s[rb + n];
    float c1_1 = C1[rb + 16 + n], c1s_1 = C1s[rb + 16 + n];

    // B staging: wave w stages tp=w, all 8 col-fragments (p = w*8 + c)
    const char* srcB[8];
    char* dstB[8];
#pragma unroll
    for (int i = 0; i < 8; ++i) {
        srcB[i] = (const char*)(WhT + (size_t)(i * 16 + n) * NN +
                                (size_t)kt0 * 128 + w * 32 + kg * 8);
        dstB[i] = lB + (w * 8 + i) * 1024 + lane * 16;
    }
    const char* srcE = (const char*)(E2 + (size_t)kt0 * 128) + lane * 16;

    const int* pA0 = A + (size_t)(rb + n) * NN + kb * 1024 + kg * 8;
    const int* pA1 = pA0 + (size_t)16 * NN;

    i32x4 ar[16];               // [grp*8 + tp*2 + half], one tile ahead
    u32 a_cur0, a_cur1;

    // prologue: A tile0 -> regs; B/E tile0 -> LDS buf0
#pragma unroll
    for (int tp = 0; tp < 4; ++tp) {
        ar[tp * 2 + 0]     = __builtin_nontemporal_load((const i32x4*)(pA0 + tp * 32));
        ar[tp * 2 + 1]     = __builtin_nontemporal_load((const i32x4*)(pA0 + tp * 32 + 4));
        ar[8 + tp * 2 + 0] = __builtin_nontemporal_load((const i32x4*)(pA1 + tp * 32));
        ar[8 + tp * 2 + 1] = __builtin_nontemporal_load((const i32x4*)(pA1 + tp * 32 + 4));
    }
#pragma unroll
    for (int i = 0; i < 8; ++i) async_ld16(srcB[i], dstB[i]);
    if (w == 0) async_ld16(srcE, lE + lane * 16);
    {
        u32 b0 = 0, b1 = 0;
#pragma unroll
        for (int tp = 0; tp < 4; ++tp) {
            PACK4(b0, ar[tp * 2 + 0], tp * 8);
            PACK4(b0, ar[tp * 2 + 1], tp * 8 + 4);
            PACK4(b1, ar[8 + tp * 2 + 0], tp * 8);
            PACK4(b1, ar[8 + tp * 2 + 1], tp * 8 + 4);
        }
        a_cur0 = b0; a_cur1 = b1;
    }

    short8 ones;
#pragma unroll
    for (int j = 0; j < 8; ++j) ones[j] = (short)0x3F80;  // bf16 1.0

    f32x4 acc0[8], acc1[8];
#pragma unroll
    for (int c = 0; c < 8; ++c) {
        acc0[c] = (f32x4){0.f, 0.f, 0.f, 0.f};
        acc1[c] = (f32x4){0.f, 0.f, 0.f, 0.f};
    }
    f32x4 accl0 = (f32x4){0.f, 0.f, 0.f, 0.f};
    f32x4 accl1 = (f32x4){0.f, 0.f, 0.f, 0.f};

    __syncthreads();

    for (int kt = 0; kt < 8; ++kt) {
        int buf = kt & 1;
        if (kt < 7) {
            // issue next A tile (consumed at pack below; HBM latency hides
            // under the MFMA/LDS section)
#pragma unroll
            for (int tp = 0; tp < 4; ++tp) {
                ar[tp * 2 + 0]     = __builtin_nontemporal_load((const i32x4*)(pA0 + (kt + 1) * 128 + tp * 32));
                ar[tp * 2 + 1]     = __builtin_nontemporal_load((const i32x4*)(pA0 + (kt + 1) * 128 + tp * 32 + 4));
                ar[8 + tp * 2 + 0] = __builtin_nontemporal_load((const i32x4*)(pA1 + (kt + 1) * 128 + tp * 32));
                ar[8 + tp * 2 + 1] = __builtin_nontemporal_load((const i32x4*)(pA1 + (kt + 1) * 128 + tp * 32 + 4));
            }
            int bo = (buf ^ 1) * 32768;
#pragma unroll
            for (int i = 0; i < 8; ++i)
                async_ld16(srcB[i] + (kt + 1) * 256, dstB[i] + bo);
            if (w == 0)
                async_ld16(srcE + (kt + 1) * 1024, lE + (buf ^ 1) * 1024 + lane * 16);
        }
        const char* bB = lB + buf * 32768;
        const float* bE = (const float*)(lE + buf * 1024);
#pragma unroll
        for (int tp = 0; tp < 4; ++tp) {
            // 8 (ep,en) pairs for this lane's 8 k-slots (broadcast across n)
            const float4* ev = (const float4*)(bE + (tp * 32 + kg * 8) * 2);
            float pe[16];
            *(float4*)(pe + 0)  = ev[0];
            *(float4*)(pe + 4)  = ev[1];
            *(float4*)(pe + 8)  = ev[2];
            *(float4*)(pe + 12) = ev[3];
            u32 ab0 = (a_cur0 >> (tp * 8)) & 0xffu;
            u32 ab1 = (a_cur1 >> (tp * 8)) & 0xffu;
            short8 af0, af1;
#pragma unroll
            for (int u = 0; u < 8; ++u) {
                // exp(leaky(s1+s2)) = max(e^s1 e^s2, e^.2s1 e^.2s2)
                float w0 = fmaxf(c1_0 * pe[2 * u], c1s_0 * pe[2 * u + 1]);
                float w1 = fmaxf(c1_1 * pe[2 * u], c1s_1 * pe[2 * u + 1]);
                af0[u] = ((ab0 >> u) & 1u) ? (short)f2bf(w0) : (short)0;
                af1[u] = ((ab1 >> u) & 1u) ? (short)f2bf(w1) : (short)0;
            }
            const short8* bb = (const short8*)(bB + tp * 8192);
#pragma unroll
            for (int c = 0; c < 8; ++c) {
                short8 bf = bb[c * 64 + lane];   // read ONCE, feed two MFMAs
                acc0[c] = __builtin_amdgcn_mfma_f32_16x16x32_bf16(af0, bf, acc0[c], 0, 0, 0);
                acc1[c] = __builtin_amdgcn_mfma_f32_16x16x32_bf16(af1, bf, acc1[c], 0, 0, 0);
            }
            accl0 = __builtin_amdgcn_mfma_f32_16x16x32_bf16(af0, ones, accl0, 0, 0, 0);
            accl1 = __builtin_amdgcn_mfma_f32_16x16x32_bf16(af1, ones, accl1, 0, 0, 0);
        }
        if (kt < 7) {   // pack next tile's masks (waits the A loads here)
            u32 b0 = 0, b1 = 0;
#pragma unroll
            for (int tp = 0; tp < 4; ++tp) {
                PACK4(b0, ar[tp * 2 + 0], tp * 8);
                PACK4(b0, ar[tp * 2 + 1], tp * 8 + 4);
                PACK4(b1, ar[8 + tp * 2 + 0], tp * 8);
                PACK4(b1, ar[8 + tp * 2 + 1], tp * 8 + 4);
            }
            a_cur0 = b0; a_cur1 = b1;
        }
        __syncthreads();
    }

    // epilogue. C/D layout: col = lane&15, row = (lane>>4)*4 + reg  [m89]
    float* Hpb = Hp + (size_t)kb * (NN * DD);
#pragma unroll
    for (int c = 0; c < 8; ++c)
#pragma unroll
        for (int r = 0; r < 4; ++r) {
            Hpb[(size_t)(rb + kg * 4 + r) * DD + c * 16 + n]      = acc0[c][r];
            Hpb[(size_t)(rb + 16 + kg * 4 + r) * DD + c * 16 + n] = acc1[c][r];
        }
    if (n == 0) {
        float* Lpb = Lp + (size_t)kb * NN;
#pragma unroll
        for (int r = 0; r < 4; ++r) {
            Lpb[rb + kg * 4 + r]      = accl0[r];
            Lpb[rb + 16 + kg * 4 + r] = accl1[r];
        }
    }
}

// ---------------- K4: combine split-K partials, normalize ----------------
__global__ void k4_final(const float* __restrict__ Hp, const float* __restrict__ Lp,
                         float* __restrict__ out) {
    int idx = blockIdx.x * 256 + threadIdx.x;
    int i = idx >> 7;
    float sv = 0.f, l = 0.f;
#pragma unroll
    for (int kb = 0; kb < 8; ++kb) {
        sv += Hp[(size_t)kb * (NN * DD) + idx];
        l  += Lp[(size_t)kb * NN + i];
    }
    out[idx] = sv / l;
}

extern "C" void kernel_launch(void* const* d_in, const int* in_sizes, int n_in,
                              void* d_out, int out_size, void* d_ws, size_t ws_size,
                              hipStream_t stream) {
    const int*   A  = (const int*)d_in[0];
    const float* X  = (const float*)d_in[1];
    const float* Ws = (const float*)d_in[2];
    const float* a  = (const float*)d_in[3];
    float* out = (float*)d_out;

    char* ws = (char*)d_ws;
    // Layout (~35.3 MB):
    //   [0, 2M)        WhT bf16 [d][srcrow]
    //   [2M, +32K)     C1
    //   [+32K, +64K)   C1s
    //   [+64K, +128K)  E2 (float2)
    //   [3M, 35M)      Hp (8 split-K partials, 4MB each)
    //   [35M, +256K)   Lp (8 partials, 32KB each)
    ushort* WhT = (ushort*)(ws);
    float*  C1  = (float*)(ws + (2u << 20));
    float*  C1s = (float*)(ws + (2u << 20) + (32u << 10));
    float2* E2  = (float2*)(ws + (2u << 20) + (64u << 10));
    float*  Hp  = (float*)(ws + (3u << 20));
    float*  Lp  = (float*)(ws + (35u << 20));

    k12_gemm<<<256, 256, 0, stream>>>(X, Ws, a, WhT, C1, C1s, E2);
    k3_main<<<dim3(64, 8), 256, 0, stream>>>(A, WhT, C1, C1s, E2, Hp, Lp);
    k4_final<<<4096, 256, 0, stream>>>(Hp, Lp, out);
}

// Round 6
// 407.785 us; speedup vs baseline: 1.1317x; 1.0398x over previous
//
#include <hip/hip_runtime.h>
#include <hip/hip_bf16.h>

#define NN 8192
#define DD 128

typedef __attribute__((ext_vector_type(8))) short short8;
typedef __attribute__((ext_vector_type(4))) float f32x4;
typedef __attribute__((ext_vector_type(4))) int i32x4;
typedef unsigned int u32;

__device__ __forceinline__ ushort f2bf(float f) {
    __hip_bfloat16 h = __float2bfloat16(f);
    return *(ushort*)&h;
}

// async 16B/lane global->LDS; LDS dest must be wave-uniform base + lane*16.
__device__ __forceinline__ void async_ld16(const void* g, void* l) {
    __builtin_amdgcn_global_load_lds(
        (const __attribute__((address_space(1))) u32*)g,
        (__attribute__((address_space(3))) u32*)l, 16, 0, 0);
}

// ---------------- K12: Wh = X @ Ws fused with per-row scalars + bf16 transpose ----
// 256 blocks x 256 thr; 32 rows/block; 4x4 register tile per thread.
// At end of k-loop each thread's acc holds Wh[r0..r0+3][c0..c0+3]; reduce
// across the 32 threads of a row-group for s1/s2 (shfl), and emit WhT bf16
// through an 8KB LDS transpose tile. Wh fp32 never touches HBM.
__global__ __launch_bounds__(256) void k12_gemm(const float* __restrict__ X,
                                                const float* __restrict__ Ws,
                                                const float* __restrict__ a,
                                                ushort* __restrict__ WhT,
                                                float* __restrict__ C1,
                                                float* __restrict__ C1s,
                                                float2* __restrict__ E2) {
    __shared__ float lWs[128 * 132];   // [k][c] pad 132
    __shared__ float lX[32 * 132];     // [r][c] pad 132
    __shared__ ushort lT2[128 * 32];   // [c][r] bf16 transpose staging
    __shared__ float la[256];
    int t = threadIdx.x, bx = blockIdx.x;
    la[t] = a[t];
    const float4* Ws4 = (const float4*)Ws;
    const float4* X4 = (const float4*)X;
    for (int j = 0; j < 16; ++j) {
        int u = j * 256 + t;           // 0..4095 float4s of Ws
        int k = u >> 5, c4 = u & 31;
        *(float4*)&lWs[k * 132 + c4 * 4] = Ws4[u];
    }
    for (int j = 0; j < 4; ++j) {
        int u = j * 256 + t;           // 0..1023 float4s of X tile
        int r = u >> 5, c4 = u & 31;
        *(float4*)&lX[r * 132 + c4 * 4] = X4[bx * 1024 + u];
    }
    __syncthreads();
    int r0 = (t >> 5) * 4, c0 = (t & 31) * 4;
    float acc[4][4];
#pragma unroll
    for (int i = 0; i < 4; ++i)
#pragma unroll
        for (int j = 0; j < 4; ++j) acc[i][j] = 0.f;
#pragma unroll 4
    for (int k = 0; k < 128; ++k) {
        float4 wv = *(const float4*)&lWs[k * 132 + c0];
        float x0 = lX[(r0 + 0) * 132 + k];
        float x1 = lX[(r0 + 1) * 132 + k];
        float x2 = lX[(r0 + 2) * 132 + k];
        float x3 = lX[(r0 + 3) * 132 + k];
#pragma unroll
        for (int j = 0; j < 4; ++j) {
            acc[0][j] += x0 * ((const float*)&wv)[j];
            acc[1][j] += x1 * ((const float*)&wv)[j];
            acc[2][j] += x2 * ((const float*)&wv)[j];
            acc[3][j] += x3 * ((const float*)&wv)[j];
        }
    }
    // bf16 transpose staging
#pragma unroll
    for (int i = 0; i < 4; ++i)
#pragma unroll
        for (int j = 0; j < 4; ++j)
            lT2[(c0 + j) * 32 + r0 + i] = f2bf(acc[i][j]);
    // per-row scalars: s1 = Wh[r].a1, s2 = Wh[r].a2
    float p1[4], p2[4];
#pragma unroll
    for (int i = 0; i < 4; ++i) {
        p1[i] = 0.f; p2[i] = 0.f;
#pragma unroll
        for (int j = 0; j < 4; ++j) {
            p1[i] += acc[i][j] * la[c0 + j];
            p2[i] += acc[i][j] * la[128 + c0 + j];
        }
    }
#pragma unroll
    for (int m = 1; m < 32; m <<= 1) {
#pragma unroll
        for (int i = 0; i < 4; ++i) {
            p1[i] += __shfl_xor(p1[i], m);
            p2[i] += __shfl_xor(p2[i], m);
        }
    }
    if ((t & 31) == 0) {
#pragma unroll
        for (int i = 0; i < 4; ++i) {
            int row = bx * 32 + r0 + i;
            C1[row]  = __expf(p1[i]);
            C1s[row] = __expf(0.2f * p1[i]);
            E2[row]  = make_float2(__expf(p2[i]), __expf(0.2f * p2[i]));
        }
    }
    __syncthreads();
    // WhT[d][srcrow]: thread t -> d=t>>1, half=t&1; 32B contiguous
    {
        int d = t >> 1, hf = t & 1;
        uint4* dst = (uint4*)&WhT[(size_t)d * NN + bx * 32 + hf * 16];
        const uint4* src = (const uint4*)&lT2[d * 32 + hf * 16];
        dst[0] = src[0];
        dst[1] = src[1];
    }
}

// ---------------- K3: masked-softmax GEMM, A streamed + packed in-kernel ----------
// grid (64 rowblocks, 16 ksplit) x 256 thr (4 waves). Each wave owns 32 rows
// (two 16-row groups) and ALL 128 cols: every B-fragment ds_read feeds TWO
// MFMAs, exp-weight built once per (row,k) globally.
// KT=64 k-tiles: LDS = 32KB B-dbuf + 2KB E-dbuf -> 3 blocks/CU (12 waves/CU)
// for phase-diverse HBM streaming (fix for the lockstep burst-drain stall).
// A: int32 0/1, loaded direct from HBM one tile ahead into 8 i32x4 regs,
// packed to 2 mask dwords after the MFMA section. Nontemporal A stream.
// Row sums via MFMA against all-ones B. Split-K partials; NO atomics.
#define PACK4(b, v, sh)                                     \
    b |= (u32)((v).x & 1) << (sh);                          \
    b |= (u32)((v).y & 1) << ((sh) + 1);                    \
    b |= (u32)((v).z & 1) << ((sh) + 2);                    \
    b |= (u32)((v).w & 1) << ((sh) + 3);

__global__ __launch_bounds__(256, 3) void k3_main(
    const int* __restrict__ A, const ushort* __restrict__ WhT,
    const float* __restrict__ C1, const float* __restrict__ C1s,
    const float2* __restrict__ E2,
    float* __restrict__ Hp, float* __restrict__ Lp) {

    __shared__ __align__(16) char lB[2 * 16384];  // [buf][(tp*8+c)*1024 + lane*16]
    __shared__ __align__(16) char lE[2 * 1024];   // [pairbuf][float2 for 128 k]

    int tid = threadIdx.x;
    int lane = tid & 63;
    int w = tid >> 6;           // 4 waves
    int n = lane & 15;
    int kg = lane >> 4;

    int bx = blockIdx.x;        // 64 row-blocks (128 rows each)
    int kb = blockIdx.y;        // 16 k-splits (512 k each)
    int rb = bx * 128 + w * 32; // wave's 32 rows (two 16-row groups)

    float c1_0 = C1[rb + n],      c1s_0 = C1s[rb + n];
    float c1_1 = C1[rb + 16 + n], c1s_1 = C1s[rb + 16 + n];

    // B staging: wave w stages fragments p = 4w..4w+3 (p = tp*8 + c)
    const char* srcB[4];
    char* dstB[4];
#pragma unroll
    for (int i = 0; i < 4; ++i) {
        int p = 4 * w + i;
        int c = p & 7, tp = p >> 3;
        srcB[i] = (const char*)(WhT + (size_t)(c * 16 + n) * NN +
                                (size_t)kb * 512 + tp * 32 + kg * 8);
        dstB[i] = lB + p * 1024 + lane * 16;
    }
    // E staging: per kt-PAIR (128 k = 1024 B, full-wave DMA)
    const char* srcE = (const char*)(E2 + (size_t)kb * 512) + lane * 16;

    const int* pA0 = A + (size_t)(rb + n) * NN + (size_t)kb * 512 + kg * 8;
    const int* pA1 = pA0 + (size_t)16 * NN;

    i32x4 ar[8];                // [grp*4 + tp*2 + half], one tile ahead
    u32 a_cur0, a_cur1;

    // prologue: A tile0 -> regs; B tile0 -> buf0; E pair0 -> buf0
#pragma unroll
    for (int tp = 0; tp < 2; ++tp) {
        ar[tp * 2 + 0]     = __builtin_nontemporal_load((const i32x4*)(pA0 + tp * 32));
        ar[tp * 2 + 1]     = __builtin_nontemporal_load((const i32x4*)(pA0 + tp * 32 + 4));
        ar[4 + tp * 2 + 0] = __builtin_nontemporal_load((const i32x4*)(pA1 + tp * 32));
        ar[4 + tp * 2 + 1] = __builtin_nontemporal_load((const i32x4*)(pA1 + tp * 32 + 4));
    }
#pragma unroll
    for (int i = 0; i < 4; ++i) async_ld16(srcB[i], dstB[i]);
    if (w == 0) async_ld16(srcE, lE + lane * 16);
    {
        u32 b0 = 0, b1 = 0;
#pragma unroll
        for (int tp = 0; tp < 2; ++tp) {
            PACK4(b0, ar[tp * 2 + 0], tp * 8);
            PACK4(b0, ar[tp * 2 + 1], tp * 8 + 4);
            PACK4(b1, ar[4 + tp * 2 + 0], tp * 8);
            PACK4(b1, ar[4 + tp * 2 + 1], tp * 8 + 4);
        }
        a_cur0 = b0; a_cur1 = b1;
    }

    short8 ones;
#pragma unroll
    for (int j = 0; j < 8; ++j) ones[j] = (short)0x3F80;  // bf16 1.0

    f32x4 acc0[8], acc1[8];
#pragma unroll
    for (int c = 0; c < 8; ++c) {
        acc0[c] = (f32x4){0.f, 0.f, 0.f, 0.f};
        acc1[c] = (f32x4){0.f, 0.f, 0.f, 0.f};
    }
    f32x4 accl0 = (f32x4){0.f, 0.f, 0.f, 0.f};
    f32x4 accl1 = (f32x4){0.f, 0.f, 0.f, 0.f};

    __syncthreads();

    for (int kt = 0; kt < 8; ++kt) {   // 8 x 64-k tiles
        int buf = kt & 1;
        if (kt < 7) {
            // issue next A tile (consumed at pack below)
#pragma unroll
            for (int tp = 0; tp < 2; ++tp) {
                ar[tp * 2 + 0]     = __builtin_nontemporal_load((const i32x4*)(pA0 + (kt + 1) * 64 + tp * 32));
                ar[tp * 2 + 1]     = __builtin_nontemporal_load((const i32x4*)(pA0 + (kt + 1) * 64 + tp * 32 + 4));
                ar[4 + tp * 2 + 0] = __builtin_nontemporal_load((const i32x4*)(pA1 + (kt + 1) * 64 + tp * 32));
                ar[4 + tp * 2 + 1] = __builtin_nontemporal_load((const i32x4*)(pA1 + (kt + 1) * 64 + tp * 32 + 4));
            }
            int bo = (buf ^ 1) * 16384;
#pragma unroll
            for (int i = 0; i < 4; ++i)
                async_ld16(srcB[i] + (kt + 1) * 128, dstB[i] + bo);
        }
        if (w == 1 && (kt & 1) == 0 && kt < 6)   // stage E pair kt/2+1
            async_ld16(srcE + (kt / 2 + 1) * 1024,
                       lE + (((kt >> 1) + 1) & 1) * 1024 + lane * 16);

        const char* bB = lB + buf * 16384;
        const float* bE = (const float*)(lE + ((kt >> 1) & 1) * 1024) + (kt & 1) * 128;
#pragma unroll
        for (int tp = 0; tp < 2; ++tp) {
            // 8 (ep,en) pairs for this lane's 8 k-slots (broadcast across n)
            const float4* ev = (const float4*)(bE + (tp * 32 + kg * 8) * 2);
            float pe[16];
            *(float4*)(pe + 0)  = ev[0];
            *(float4*)(pe + 4)  = ev[1];
            *(float4*)(pe + 8)  = ev[2];
            *(float4*)(pe + 12) = ev[3];
            u32 ab0 = (a_cur0 >> (tp * 8)) & 0xffu;
            u32 ab1 = (a_cur1 >> (tp * 8)) & 0xffu;
            short8 af0, af1;
#pragma unroll
            for (int u = 0; u < 8; ++u) {
                // exp(leaky(s1+s2)) = max(e^s1 e^s2, e^.2s1 e^.2s2)
                float w0 = fmaxf(c1_0 * pe[2 * u], c1s_0 * pe[2 * u + 1]);
                float w1 = fmaxf(c1_1 * pe[2 * u], c1s_1 * pe[2 * u + 1]);
                af0[u] = ((ab0 >> u) & 1u) ? (short)f2bf(w0) : (short)0;
                af1[u] = ((ab1 >> u) & 1u) ? (short)f2bf(w1) : (short)0;
            }
            const short8* bb = (const short8*)(bB + tp * 8192);
#pragma unroll
            for (int c = 0; c < 8; ++c) {
                short8 bf = bb[c * 64 + lane];   // read ONCE, feed two MFMAs
                acc0[c] = __builtin_amdgcn_mfma_f32_16x16x32_bf16(af0, bf, acc0[c], 0, 0, 0);
                acc1[c] = __builtin_amdgcn_mfma_f32_16x16x32_bf16(af1, bf, acc1[c], 0, 0, 0);
            }
            accl0 = __builtin_amdgcn_mfma_f32_16x16x32_bf16(af0, ones, accl0, 0, 0, 0);
            accl1 = __builtin_amdgcn_mfma_f32_16x16x32_bf16(af1, ones, accl1, 0, 0, 0);
        }
        if (kt < 7) {   // pack next tile's masks (waits the A loads here)
            u32 b0 = 0, b1 = 0;
#pragma unroll
            for (int tp = 0; tp < 2; ++tp) {
                PACK4(b0, ar[tp * 2 + 0], tp * 8);
                PACK4(b0, ar[tp * 2 + 1], tp * 8 + 4);
                PACK4(b1, ar[4 + tp * 2 + 0], tp * 8);
                PACK4(b1, ar[4 + tp * 2 + 1], tp * 8 + 4);
            }
            a_cur0 = b0; a_cur1 = b1;
        }
        __syncthreads();
    }

    // epilogue. C/D layout: col = lane&15, row = (lane>>4)*4 + reg  [m89]
    float* Hpb = Hp + (size_t)kb * (NN * DD);
#pragma unroll
    for (int c = 0; c < 8; ++c)
#pragma unroll
        for (int r = 0; r < 4; ++r) {
            Hpb[(size_t)(rb + kg * 4 + r) * DD + c * 16 + n]      = acc0[c][r];
            Hpb[(size_t)(rb + 16 + kg * 4 + r) * DD + c * 16 + n] = acc1[c][r];
        }
    if (n == 0) {
        float* Lpb = Lp + (size_t)kb * NN;
#pragma unroll
        for (int r = 0; r < 4; ++r) {
            Lpb[rb + kg * 4 + r]      = accl0[r];
            Lpb[rb + 16 + kg * 4 + r] = accl1[r];
        }
    }
}

// ---------------- K4: combine split-K partials, normalize (float4) ----------------
// 262144 float4s total: 1024 blocks x 256 thr.
__global__ void k4_final(const float* __restrict__ Hp, const float* __restrict__ Lp,
                         float* __restrict__ out) {
    int g = blockIdx.x * 256 + threadIdx.x;   // 0..262143 float4s
    int i = g >> 5;                            // row (128 f / 4 = 32 f4 per row)
    float4 sv = make_float4(0.f, 0.f, 0.f, 0.f);
    float l = 0.f;
#pragma unroll
    for (int kb = 0; kb < 16; ++kb) {
        float4 v = *(const float4*)(Hp + (size_t)kb * (NN * DD) + (size_t)g * 4);
        sv.x += v.x; sv.y += v.y; sv.z += v.z; sv.w += v.w;
        l += Lp[(size_t)kb * NN + i];
    }
    float r = 1.f / l;
    *(float4*)(out + (size_t)g * 4) = make_float4(sv.x * r, sv.y * r, sv.z * r, sv.w * r);
}

extern "C" void kernel_launch(void* const* d_in, const int* in_sizes, int n_in,
                              void* d_out, int out_size, void* d_ws, size_t ws_size,
                              hipStream_t stream) {
    const int*   A  = (const int*)d_in[0];
    const float* X  = (const float*)d_in[1];
    const float* Ws = (const float*)d_in[2];
    const float* a  = (const float*)d_in[3];
    float* out = (float*)d_out;

    char* ws = (char*)d_ws;
    // Layout (~67.5 MB):
    //   [0, 2M)        WhT bf16 [d][srcrow]
    //   [2M, +32K)     C1
    //   [+32K, +64K)   C1s
    //   [+64K, +128K)  E2 (float2)
    //   [3M, 67M)      Hp (16 split-K partials, 4MB each)
    //   [67M, +512K)   Lp (16 partials, 32KB each)
    ushort* WhT = (ushort*)(ws);
    float*  C1  = (float*)(ws + (2u << 20));
    float*  C1s = (float*)(ws + (2u << 20) + (32u << 10));
    float2* E2  = (float2*)(ws + (2u << 20) + (64u << 10));
    float*  Hp  = (float*)(ws + (3u << 20));
    float*  Lp  = (float*)(ws + (67u << 20));

    k12_gemm<<<256, 256, 0, stream>>>(X, Ws, a, WhT, C1, C1s, E2);
    k3_main<<<dim3(64, 16), 256, 0, stream>>>(A, WhT, C1, C1s, E2, Hp, Lp);
    k4_final<<<1024, 256, 0, stream>>>(Hp, Lp, out);
}